// Round 3
// baseline (90.603 us; speedup 1.0000x reference)
//
#include <hip/hip_runtime.h>

// SparseVoxelConverter: depth -> xyz -> voxel indices, masked.
// B=16, H=W=512, N = B*H*W = 4,194,304.
// Output (concatenated flat, all written as float32):
//   [0,   4N) : indices [N,4]  (b, vx, vy, vz) or -1 if masked
//   [4N,  7N) : values  [N,3]  rgb (NHWC) or 0 if masked
//   [7N,  8N) : mask    [N]    1.0 / 0.0
//
// R3: non-temporal stores via clang native vector type (HIP float4 is a
// struct and the builtin rejects it). Outputs are write-only -> stream past
// L2/LLC so the 67 MB of inputs stay L3-resident across graph replays.

#define SVC_B  16
#define SVC_H  512
#define SVC_W  512
#define SVC_HW (SVC_H * SVC_W)       // 262144 = 2^18
#define SVC_N  (SVC_B * SVC_HW)      // 4,194,304

typedef float f32x4 __attribute__((ext_vector_type(4)));

__global__ __launch_bounds__(256)
void svc_kernel(const float* __restrict__ rgb,
                const float* __restrict__ depth,
                float* __restrict__ out_idx,   // [N*4]
                float* __restrict__ out_val,   // [N*3]
                float* __restrict__ out_mask)  // [N]
{
    const int tid = blockIdx.x * blockDim.x + threadIdx.x;
    const int n0  = tid << 2;                  // first of 4 consecutive points
    if (n0 >= SVC_N) return;

    const int b   = n0 >> 18;                  // / HW
    const int rem = n0 & (SVC_HW - 1);         // within-image offset
    const int v   = rem >> 9;                  // / W
    const int u0  = rem & (SVC_W - 1);         // % W  (4 points share b, v)

    // Coalesced vector loads: depth + 3 rgb channel streams (cached: inputs
    // are re-read every replay and fit in L3 once outputs stop polluting it).
    const f32x4 d4 = *reinterpret_cast<const f32x4*>(depth + (size_t)b * SVC_HW + rem);
    const float* rgbb = rgb + (size_t)b * 3 * SVC_HW + rem;
    const f32x4 r4 = *reinterpret_cast<const f32x4*>(rgbb);
    const f32x4 g4 = *reinterpret_cast<const f32x4*>(rgbb + SVC_HW);
    const f32x4 b4 = *reinterpret_cast<const f32x4*>(rgbb + 2 * SVC_HW);

    const float yb = (float)v - 256.0f;        // (v - cy), same for all 4
    const float bf = (float)b;

    float oi[16];  // indices, 4 pts x 4
    float ov[12];  // values,  4 pts x 3
    float om[4];   // mask

    #pragma unroll
    for (int i = 0; i < 4; ++i) {
        const float d = d4[i];
        const bool m = (d > 0.1f) & (d < 10.0f);
        // x = (u - cx) * d / fx ; fx = cx = 256
        const float x = ((float)(u0 + i) - 256.0f) * d * (1.0f / 256.0f);
        const float y = yb * d * (1.0f / 256.0f);
        // norm = (coord + 1) * 32 ; vox = clip(trunc(norm), 0, 63)
        const float vx = fminf(fmaxf(truncf((x + 1.0f) * 32.0f), 0.0f), 63.0f);
        const float vy = fminf(fmaxf(truncf((y + 1.0f) * 32.0f), 0.0f), 63.0f);
        const float vz = fminf(fmaxf(truncf((d + 1.0f) * 32.0f), 0.0f), 63.0f);

        oi[i * 4 + 0] = m ? bf : -1.0f;
        oi[i * 4 + 1] = m ? vx : -1.0f;
        oi[i * 4 + 2] = m ? vy : -1.0f;
        oi[i * 4 + 3] = m ? vz : -1.0f;
        ov[i * 3 + 0] = m ? r4[i] : 0.0f;
        ov[i * 3 + 1] = m ? g4[i] : 0.0f;
        ov[i * 3 + 2] = m ? b4[i] : 0.0f;
        om[i] = m ? 1.0f : 0.0f;
    }

    // Vectorized NON-TEMPORAL stores. n0 is a multiple of 4 -> all segments
    // 16B-aligned. Outputs are write-only: stream past L2/LLC.
    f32x4* pi = reinterpret_cast<f32x4*>(out_idx + (size_t)n0 * 4);   // 64 B
    __builtin_nontemporal_store((f32x4){oi[0],  oi[1],  oi[2],  oi[3]},  pi + 0);
    __builtin_nontemporal_store((f32x4){oi[4],  oi[5],  oi[6],  oi[7]},  pi + 1);
    __builtin_nontemporal_store((f32x4){oi[8],  oi[9],  oi[10], oi[11]}, pi + 2);
    __builtin_nontemporal_store((f32x4){oi[12], oi[13], oi[14], oi[15]}, pi + 3);

    f32x4* pv = reinterpret_cast<f32x4*>(out_val + (size_t)n0 * 3);   // 48 B
    __builtin_nontemporal_store((f32x4){ov[0], ov[1], ov[2],  ov[3]},  pv + 0);
    __builtin_nontemporal_store((f32x4){ov[4], ov[5], ov[6],  ov[7]},  pv + 1);
    __builtin_nontemporal_store((f32x4){ov[8], ov[9], ov[10], ov[11]}, pv + 2);

    __builtin_nontemporal_store((f32x4){om[0], om[1], om[2], om[3]},
                                reinterpret_cast<f32x4*>(out_mask + n0));
}

extern "C" void kernel_launch(void* const* d_in, const int* in_sizes, int n_in,
                              void* d_out, int out_size, void* d_ws, size_t ws_size,
                              hipStream_t stream) {
    const float* rgb   = (const float*)d_in[0];
    const float* depth = (const float*)d_in[1];

    float* out_idx  = (float*)d_out;                     // N*4
    float* out_val  = out_idx + (size_t)SVC_N * 4;       // N*3
    float* out_mask = out_val + (size_t)SVC_N * 3;       // N

    const int threads = 256;
    const int groups  = SVC_N / 4;                       // 1,048,576
    const int blocks  = groups / threads;                // 4096
    svc_kernel<<<blocks, threads, 0, stream>>>(rgb, depth, out_idx, out_val, out_mask);
}

// Round 4
// 53.094 us; speedup vs baseline: 1.7065x; 1.7065x over previous
//
#include <hip/hip_runtime.h>

// SparseVoxelConverter: depth -> xyz -> voxel indices, masked.
// B=16, H=W=512, N = B*H*W = 4,194,304.
// Output (concatenated flat, all written as float32):
//   [0,   4N) : indices [N,4]  (b, vx, vy, vz) or -1 if masked
//   [4N,  7N) : values  [N,3]  rgb (NHWC) or 0 if masked
//   [7N,  8N) : mask    [N]    1.0 / 0.0
//
// R4: plain cached stores (R3 showed nt-stores are a 2x regression on
// gfx950 — slow write path). 8 points/thread for deeper per-wave memory
// queues (more MLP, fewer address calcs).

#define SVC_B  16
#define SVC_H  512
#define SVC_W  512
#define SVC_HW (SVC_H * SVC_W)       // 262144 = 2^18
#define SVC_N  (SVC_B * SVC_HW)      // 4,194,304

typedef float f32x4 __attribute__((ext_vector_type(4)));

__global__ __launch_bounds__(256)
void svc_kernel(const float* __restrict__ rgb,
                const float* __restrict__ depth,
                float* __restrict__ out_idx,   // [N*4]
                float* __restrict__ out_val,   // [N*3]
                float* __restrict__ out_mask)  // [N]
{
    const int tid = blockIdx.x * blockDim.x + threadIdx.x;
    const int n0  = tid << 3;                  // first of 8 consecutive points
    if (n0 >= SVC_N) return;

    const int b   = n0 >> 18;                  // / HW
    const int rem = n0 & (SVC_HW - 1);         // within-image offset
    const int v   = rem >> 9;                  // / W
    const int u0  = rem & (SVC_W - 1);         // % W  (8 points share b, v; W=512 divisible by 8)

    // Coalesced vector loads: depth + 3 rgb channel streams, 2x float4 each.
    const float* dp   = depth + (size_t)b * SVC_HW + rem;
    const float* rgbb = rgb + (size_t)b * 3 * SVC_HW + rem;
    const f32x4 d4a = *reinterpret_cast<const f32x4*>(dp);
    const f32x4 d4b = *reinterpret_cast<const f32x4*>(dp + 4);
    const f32x4 r4a = *reinterpret_cast<const f32x4*>(rgbb);
    const f32x4 r4b = *reinterpret_cast<const f32x4*>(rgbb + 4);
    const f32x4 g4a = *reinterpret_cast<const f32x4*>(rgbb + SVC_HW);
    const f32x4 g4b = *reinterpret_cast<const f32x4*>(rgbb + SVC_HW + 4);
    const f32x4 b4a = *reinterpret_cast<const f32x4*>(rgbb + 2 * SVC_HW);
    const f32x4 b4b = *reinterpret_cast<const f32x4*>(rgbb + 2 * SVC_HW + 4);

    const float yb = (float)v - 256.0f;        // (v - cy), same for all 8
    const float bf = (float)b;

    float dv[8] = {d4a[0], d4a[1], d4a[2], d4a[3], d4b[0], d4b[1], d4b[2], d4b[3]};
    float rv[8] = {r4a[0], r4a[1], r4a[2], r4a[3], r4b[0], r4b[1], r4b[2], r4b[3]};
    float gv[8] = {g4a[0], g4a[1], g4a[2], g4a[3], g4b[0], g4b[1], g4b[2], g4b[3]};
    float bv[8] = {b4a[0], b4a[1], b4a[2], b4a[3], b4b[0], b4b[1], b4b[2], b4b[3]};

    float oi[32];  // indices, 8 pts x 4
    float ov[24];  // values,  8 pts x 3
    float om[8];   // mask

    #pragma unroll
    for (int i = 0; i < 8; ++i) {
        const float d = dv[i];
        const bool m = (d > 0.1f) & (d < 10.0f);
        // x = (u - cx) * d / fx ; fx = cx = 256
        const float x = ((float)(u0 + i) - 256.0f) * d * (1.0f / 256.0f);
        const float y = yb * d * (1.0f / 256.0f);
        // norm = (coord + 1) * 32 ; vox = clip(trunc(norm), 0, 63)
        const float vx = fminf(fmaxf(truncf((x + 1.0f) * 32.0f), 0.0f), 63.0f);
        const float vy = fminf(fmaxf(truncf((y + 1.0f) * 32.0f), 0.0f), 63.0f);
        const float vz = fminf(fmaxf(truncf((d + 1.0f) * 32.0f), 0.0f), 63.0f);

        oi[i * 4 + 0] = m ? bf : -1.0f;
        oi[i * 4 + 1] = m ? vx : -1.0f;
        oi[i * 4 + 2] = m ? vy : -1.0f;
        oi[i * 4 + 3] = m ? vz : -1.0f;
        ov[i * 3 + 0] = m ? rv[i] : 0.0f;
        ov[i * 3 + 1] = m ? gv[i] : 0.0f;
        ov[i * 3 + 2] = m ? bv[i] : 0.0f;
        om[i] = m ? 1.0f : 0.0f;
    }

    // Vectorized stores. n0 is a multiple of 8 -> all segments 16B-aligned.
    f32x4* pi = reinterpret_cast<f32x4*>(out_idx + (size_t)n0 * 4);   // 128 B
    #pragma unroll
    for (int k = 0; k < 8; ++k)
        pi[k] = (f32x4){oi[k * 4 + 0], oi[k * 4 + 1], oi[k * 4 + 2], oi[k * 4 + 3]};

    f32x4* pv = reinterpret_cast<f32x4*>(out_val + (size_t)n0 * 3);   // 96 B
    #pragma unroll
    for (int k = 0; k < 6; ++k)
        pv[k] = (f32x4){ov[k * 4 + 0], ov[k * 4 + 1], ov[k * 4 + 2], ov[k * 4 + 3]};

    f32x4* pm = reinterpret_cast<f32x4*>(out_mask + n0);              // 32 B
    pm[0] = (f32x4){om[0], om[1], om[2], om[3]};
    pm[1] = (f32x4){om[4], om[5], om[6], om[7]};
}

extern "C" void kernel_launch(void* const* d_in, const int* in_sizes, int n_in,
                              void* d_out, int out_size, void* d_ws, size_t ws_size,
                              hipStream_t stream) {
    const float* rgb   = (const float*)d_in[0];
    const float* depth = (const float*)d_in[1];

    float* out_idx  = (float*)d_out;                     // N*4
    float* out_val  = out_idx + (size_t)SVC_N * 4;       // N*3
    float* out_mask = out_val + (size_t)SVC_N * 3;       // N

    const int threads = 256;
    const int groups  = SVC_N / 8;                       // 524,288
    const int blocks  = groups / threads;                // 2048
    svc_kernel<<<blocks, threads, 0, stream>>>(rgb, depth, out_idx, out_val, out_mask);
}

// Round 5
// 34.789 us; speedup vs baseline: 2.6044x; 1.5262x over previous
//
#include <hip/hip_runtime.h>

// SparseVoxelConverter: depth -> xyz -> voxel indices, masked.
// B=16, H=W=512, N = B*H*W = 4,194,304.
// Output (concatenated flat, all written as float32):
//   [0,   4N) : indices [N,4]  (b, vx, vy, vz) or -1 if masked
//   [4N,  7N) : values  [N,3]  rgb (NHWC) or 0 if masked
//   [7N,  8N) : mask    [N]    1.0 / 0.0
//
// R5: R1 structure (4 pts/thread, plain cached stores — nt-stores were a 2x
// regression in R3) + LDS store-staging so every global store instruction is
// perfectly lane-contiguous (dense 1 KB segments, like the 7 TB/s fill
// kernels), instead of 48/64 B lane-strided. LDS granule XOR swizzle
// L(g) = g ^ ((g>>2)&7) keeps both the b128 write phase (lane t -> granules
// 4t+j) and the contiguous read phase (lane t -> granule t+256s) spread
// across all 8 LDS bank groups.

#define SVC_B  16
#define SVC_H  512
#define SVC_W  512
#define SVC_HW (SVC_H * SVC_W)       // 262144 = 2^18
#define SVC_N  (SVC_B * SVC_HW)      // 4,194,304
#define TPB    256
#define PTS_BLK (TPB * 4)            // 1024 points per block

typedef float f32x4 __attribute__((ext_vector_type(4)));

__device__ __forceinline__ int sw(int g) { return g ^ ((g >> 2) & 7); }

__global__ __launch_bounds__(TPB)
void svc_kernel(const float* __restrict__ rgb,
                const float* __restrict__ depth,
                float* __restrict__ out_idx,   // [N*4]
                float* __restrict__ out_val,   // [N*3]
                float* __restrict__ out_mask)  // [N]
{
    __shared__ f32x4 s_idx[PTS_BLK];          // 1024 granules = 16 KB
    __shared__ f32x4 s_val[PTS_BLK * 3 / 4];  //  768 granules = 12 KB
    __shared__ f32x4 s_mask[PTS_BLK / 4];     //  256 granules =  4 KB

    const int t  = threadIdx.x;
    const int n0 = blockIdx.x * PTS_BLK + t * 4;   // first of 4 points

    const int b   = n0 >> 18;                  // / HW
    const int rem = n0 & (SVC_HW - 1);         // within-image offset
    const int v   = rem >> 9;                  // / W
    const int u0  = rem & (SVC_W - 1);         // % W (4 points share b, v)

    // Coalesced vector loads: depth + 3 rgb channel streams.
    const f32x4 d4 = *reinterpret_cast<const f32x4*>(depth + (size_t)b * SVC_HW + rem);
    const float* rgbb = rgb + (size_t)b * 3 * SVC_HW + rem;
    const f32x4 r4 = *reinterpret_cast<const f32x4*>(rgbb);
    const f32x4 g4 = *reinterpret_cast<const f32x4*>(rgbb + SVC_HW);
    const f32x4 b4 = *reinterpret_cast<const f32x4*>(rgbb + 2 * SVC_HW);

    const float yb = (float)v - 256.0f;        // (v - cy), same for all 4
    const float bf = (float)b;

    float ov[12];
    float om[4];

    #pragma unroll
    for (int i = 0; i < 4; ++i) {
        const float d = d4[i];
        const bool m = (d > 0.1f) & (d < 10.0f);
        // x = (u - cx) * d / fx ; fx = cx = 256
        const float x = ((float)(u0 + i) - 256.0f) * d * (1.0f / 256.0f);
        const float y = yb * d * (1.0f / 256.0f);
        // norm = (coord + 1) * 32 ; vox = clip(trunc(norm), 0, 63)
        const float vx = fminf(fmaxf(truncf((x + 1.0f) * 32.0f), 0.0f), 63.0f);
        const float vy = fminf(fmaxf(truncf((y + 1.0f) * 32.0f), 0.0f), 63.0f);
        const float vz = fminf(fmaxf(truncf((d + 1.0f) * 32.0f), 0.0f), 63.0f);

        s_idx[sw(t * 4 + i)] = m ? (f32x4){bf, vx, vy, vz}
                                 : (f32x4){-1.0f, -1.0f, -1.0f, -1.0f};
        ov[i * 3 + 0] = m ? r4[i] : 0.0f;
        ov[i * 3 + 1] = m ? g4[i] : 0.0f;
        ov[i * 3 + 2] = m ? b4[i] : 0.0f;
        om[i] = m ? 1.0f : 0.0f;
    }

    #pragma unroll
    for (int k = 0; k < 3; ++k)
        s_val[sw(t * 3 + k)] = (f32x4){ov[k*4+0], ov[k*4+1], ov[k*4+2], ov[k*4+3]};
    s_mask[sw(t)] = (f32x4){om[0], om[1], om[2], om[3]};

    __syncthreads();

    // Perfectly coalesced store phase: lane t writes global granule t + 256*s.
    f32x4* gi = reinterpret_cast<f32x4*>(out_idx)  + (size_t)blockIdx.x * PTS_BLK;
    #pragma unroll
    for (int s = 0; s < 4; ++s)
        gi[t + TPB * s] = s_idx[sw(t + TPB * s)];

    f32x4* gv = reinterpret_cast<f32x4*>(out_val)  + (size_t)blockIdx.x * (PTS_BLK * 3 / 4);
    #pragma unroll
    for (int s = 0; s < 3; ++s)
        gv[t + TPB * s] = s_val[sw(t + TPB * s)];

    f32x4* gm = reinterpret_cast<f32x4*>(out_mask) + (size_t)blockIdx.x * (PTS_BLK / 4);
    gm[t] = s_mask[sw(t)];
}

extern "C" void kernel_launch(void* const* d_in, const int* in_sizes, int n_in,
                              void* d_out, int out_size, void* d_ws, size_t ws_size,
                              hipStream_t stream) {
    const float* rgb   = (const float*)d_in[0];
    const float* depth = (const float*)d_in[1];

    float* out_idx  = (float*)d_out;                     // N*4
    float* out_val  = out_idx + (size_t)SVC_N * 4;       // N*3
    float* out_mask = out_val + (size_t)SVC_N * 3;       // N

    const int blocks = SVC_N / PTS_BLK;                  // 4096
    svc_kernel<<<blocks, TPB, 0, stream>>>(rgb, depth, out_idx, out_val, out_mask);
}

// Round 6
// 34.399 us; speedup vs baseline: 2.6339x; 1.0113x over previous
//
#include <hip/hip_runtime.h>

// SparseVoxelConverter: depth -> xyz -> voxel indices, masked.
// B=16, H=W=512, N = B*H*W = 4,194,304.
// Output (concatenated flat, all written as float32):
//   [0,   4N) : indices [N,4]  (b, vx, vy, vz) or -1 if masked
//   [4N,  7N) : values  [N,3]  rgb (NHWC) or 0 if masked
//   [7N,  8N) : mask    [N]    1.0 / 0.0
//
// R6: R5 structure (LDS-staged dense stores, +20% over direct strided
// stores) with occupancy pushed to 100%:
//  - mask is NOT staged (at 4 pts/thread lane t writes 16 B at byte offset
//    16t -> already perfectly lane-contiguous);
//  - one 16 KB LDS buffer reused in two drain phases (idx, then val):
//    16 KB/block -> 8 blocks/CU (wave-capped) = 32 waves/CU vs R5's 20.
// XOR granule swizzle L(g) = g ^ ((g>>2)&7) spreads both the b128 write
// phase and the contiguous read phase across all 8 LDS bank groups
// (bijective within each 8-granule stripe).

#define SVC_B  16
#define SVC_H  512
#define SVC_W  512
#define SVC_HW (SVC_H * SVC_W)       // 262144 = 2^18
#define SVC_N  (SVC_B * SVC_HW)      // 4,194,304
#define TPB    256
#define PTS_BLK (TPB * 4)            // 1024 points per block

typedef float f32x4 __attribute__((ext_vector_type(4)));

__device__ __forceinline__ int sw(int g) { return g ^ ((g >> 2) & 7); }

__global__ __launch_bounds__(TPB)
void svc_kernel(const float* __restrict__ rgb,
                const float* __restrict__ depth,
                float* __restrict__ out_idx,   // [N*4]
                float* __restrict__ out_val,   // [N*3]
                float* __restrict__ out_mask)  // [N]
{
    __shared__ f32x4 s_buf[PTS_BLK];          // 16 KB, reused idx then val

    const int t  = threadIdx.x;
    const int n0 = blockIdx.x * PTS_BLK + t * 4;   // first of 4 points

    const int b   = n0 >> 18;                  // / HW
    const int rem = n0 & (SVC_HW - 1);         // within-image offset
    const int v   = rem >> 9;                  // / W
    const int u0  = rem & (SVC_W - 1);         // % W (4 points share b, v)

    // Coalesced vector loads: depth + 3 rgb channel streams.
    const f32x4 d4 = *reinterpret_cast<const f32x4*>(depth + (size_t)b * SVC_HW + rem);
    const float* rgbb = rgb + (size_t)b * 3 * SVC_HW + rem;
    const f32x4 r4 = *reinterpret_cast<const f32x4*>(rgbb);
    const f32x4 g4 = *reinterpret_cast<const f32x4*>(rgbb + SVC_HW);
    const f32x4 b4 = *reinterpret_cast<const f32x4*>(rgbb + 2 * SVC_HW);

    const float yb = (float)v - 256.0f;        // (v - cy), same for all 4
    const float bf = (float)b;

    float ov[12];
    float om[4];

    // ---- Phase 1: indices through LDS ----
    #pragma unroll
    for (int i = 0; i < 4; ++i) {
        const float d = d4[i];
        const bool m = (d > 0.1f) & (d < 10.0f);
        // x = (u - cx) * d / fx ; fx = cx = 256
        const float x = ((float)(u0 + i) - 256.0f) * d * (1.0f / 256.0f);
        const float y = yb * d * (1.0f / 256.0f);
        // norm = (coord + 1) * 32 ; vox = clip(trunc(norm), 0, 63)
        const float vx = fminf(fmaxf(truncf((x + 1.0f) * 32.0f), 0.0f), 63.0f);
        const float vy = fminf(fmaxf(truncf((y + 1.0f) * 32.0f), 0.0f), 63.0f);
        const float vz = fminf(fmaxf(truncf((d + 1.0f) * 32.0f), 0.0f), 63.0f);

        s_buf[sw(t * 4 + i)] = m ? (f32x4){bf, vx, vy, vz}
                                 : (f32x4){-1.0f, -1.0f, -1.0f, -1.0f};
        ov[i * 3 + 0] = m ? r4[i] : 0.0f;
        ov[i * 3 + 1] = m ? g4[i] : 0.0f;
        ov[i * 3 + 2] = m ? b4[i] : 0.0f;
        om[i] = m ? 1.0f : 0.0f;
    }

    // Mask store: lane t writes bytes [16t, 16t+16) -> already dense.
    f32x4* gm = reinterpret_cast<f32x4*>(out_mask) + (size_t)blockIdx.x * (PTS_BLK / 4);
    gm[t] = (f32x4){om[0], om[1], om[2], om[3]};

    __syncthreads();

    // Dense idx drain: lane t writes global granule t + 256*s.
    f32x4* gi = reinterpret_cast<f32x4*>(out_idx) + (size_t)blockIdx.x * PTS_BLK;
    #pragma unroll
    for (int s = 0; s < 4; ++s)
        gi[t + TPB * s] = s_buf[sw(t + TPB * s)];

    __syncthreads();

    // ---- Phase 2: values through the same LDS buffer ----
    #pragma unroll
    for (int k = 0; k < 3; ++k)
        s_buf[sw(t * 3 + k)] = (f32x4){ov[k*4+0], ov[k*4+1], ov[k*4+2], ov[k*4+3]};

    __syncthreads();

    // Dense val drain.
    f32x4* gv = reinterpret_cast<f32x4*>(out_val) + (size_t)blockIdx.x * (PTS_BLK * 3 / 4);
    #pragma unroll
    for (int s = 0; s < 3; ++s)
        gv[t + TPB * s] = s_buf[sw(t + TPB * s)];
}

extern "C" void kernel_launch(void* const* d_in, const int* in_sizes, int n_in,
                              void* d_out, int out_size, void* d_ws, size_t ws_size,
                              hipStream_t stream) {
    const float* rgb   = (const float*)d_in[0];
    const float* depth = (const float*)d_in[1];

    float* out_idx  = (float*)d_out;                     // N*4
    float* out_val  = out_idx + (size_t)SVC_N * 4;       // N*3
    float* out_mask = out_val + (size_t)SVC_N * 3;       // N

    const int blocks = SVC_N / PTS_BLK;                  // 4096
    svc_kernel<<<blocks, TPB, 0, stream>>>(rgb, depth, out_idx, out_val, out_mask);
}